// Round 1
// baseline (130.830 us; speedup 1.0000x reference)
//
#include <hip/hip_runtime.h>

#define Hd     256
#define OUTD   10
#define DDEP   64
#define TLEN   8192
#define BBATCH 64
#define RPB    8

// Generic stage kernel: rows [0,sqRows) -> Pout = P*P rows; [sqRows, sqRows+nRrows)
// -> Rdst = Rsrc * P rows; [.., ..+cpRows) -> plain copy cpSrc->cpDst.
__global__ __launch_bounds__(256) void stage_kernel(
    const float* __restrict__ P, float* __restrict__ Pout,
    const float* __restrict__ Rsrc, float* __restrict__ Rdst,
    int nRrows, int sqRows,
    const float* __restrict__ cpSrc, float* __restrict__ cpDst, int cpRows)
{
    __shared__ float inrow[RPB][Hd];
    const int tid  = threadIdx.x;       // column k
    const int row0 = blockIdx.x * RPB;

    float* outp[RPB];
    #pragma unroll
    for (int r = 0; r < RPB; ++r) {
        const int row = row0 + r;
        const float* in = nullptr;
        float* out = nullptr;
        if (row < sqRows) {
            in  = P    + row * Hd;
            out = Pout + row * Hd;
        } else if (row < sqRows + nRrows) {
            const int j = row - sqRows;
            in  = Rsrc + j * Hd;
            out = Rdst + j * Hd;
        } else if (row < sqRows + nRrows + cpRows) {
            const int j = row - sqRows - nRrows;
            cpDst[j * Hd + tid] = cpSrc[j * Hd + tid];
        }
        inrow[r][tid] = in ? in[tid] : 0.0f;
        outp[r] = out;
    }
    __syncthreads();

    float acc[RPB] = {0.f, 0.f, 0.f, 0.f, 0.f, 0.f, 0.f, 0.f};
    #pragma unroll 4
    for (int j = 0; j < Hd; ++j) {
        const float p = P[j * Hd + tid];   // coalesced column load
        #pragma unroll
        for (int r = 0; r < RPB; ++r)
            acc[r] = fmaf(inrow[r][j], p, acc[r]);
    }
    #pragma unroll
    for (int r = 0; r < RPB; ++r)
        if (outp[r]) outp[r][tid] = acc[r];
}

// K[d][o] = dot(R_d[o], w1); K stored padded to stride 12 floats (48B, 16B-aligned).
__global__ __launch_bounds__(256) void k_kernel(
    const float* __restrict__ Rb, const float* __restrict__ w1,
    float* __restrict__ Kb)
{
    const int wave = threadIdx.x >> 6;
    const int lane = threadIdx.x & 63;
    const int pair = blockIdx.x * 4 + wave;     // 0..639 == d*10+o
    const int d = pair / 10;
    const int o = pair % 10;
    const float* r = Rb + pair * Hd;
    float s = 0.0f;
    #pragma unroll
    for (int i = 0; i < Hd / 64; ++i)
        s = fmaf(r[lane + i * 64], w1[lane + i * 64], s);
    #pragma unroll
    for (int off = 32; off > 0; off >>= 1)
        s += __shfl_down(s, off);
    if (lane == 0) Kb[d * 12 + o] = s;
    if (lane == 1 && o == 0) { Kb[d * 12 + 10] = 0.0f; Kb[d * 12 + 11] = 0.0f; }
}

// Causal FIR: y[b,t,o] = sum_{d<64} K[d][o]*x[b,t-d].
// Block: 256 threads, one b, 1024 t-positions (4 consecutive per thread).
__global__ __launch_bounds__(256) void conv_kernel(
    const float* __restrict__ x, const float* __restrict__ Kb,
    float* __restrict__ y)
{
    __shared__ float xs[1160];          // swizzled: phys(j) = j + (j>>5), j in [0,1088)
    __shared__ float Ks[DDEP * 12];
    const int tid  = threadIdx.x;
    const int b    = blockIdx.x >> 3;   // TLEN/1024 == 8 tiles
    const int t0   = (blockIdx.x & 7) * 1024;
    const float* xb = x + b * TLEN;

    for (int j = tid; j < 1088; j += 256) {       // xs[j] = x[b][t0-64+j]
        const int g = t0 - 64 + j;
        xs[j + (j >> 5)] = (g >= 0) ? xb[g] : 0.0f;
    }
    for (int j = tid; j < DDEP * 12; j += 256) Ks[j] = Kb[j];
    __syncthreads();

    const int ub = tid * 4;             // first of 4 consecutive t-offsets
    float acc[4][OUTD];
    #pragma unroll
    for (int i = 0; i < 4; ++i)
        #pragma unroll
        for (int o = 0; o < OUTD; ++o) acc[i][o] = 0.0f;

    float wn[4];                        // wn[i] = x value for position i at current d
    #pragma unroll
    for (int i = 0; i < 4; ++i) {
        const int j = 64 + ub + i;
        wn[i] = xs[j + (j >> 5)];
    }

    #pragma unroll 8
    for (int d = 0; d < DDEP; ++d) {
        const float4 kA = *(const float4*)&Ks[d * 12];
        const float4 kB = *(const float4*)&Ks[d * 12 + 4];
        const float2 kC = *(const float2*)&Ks[d * 12 + 8];
        #pragma unroll
        for (int i = 0; i < 4; ++i) {
            const float xv = wn[i];
            acc[i][0] = fmaf(kA.x, xv, acc[i][0]);
            acc[i][1] = fmaf(kA.y, xv, acc[i][1]);
            acc[i][2] = fmaf(kA.z, xv, acc[i][2]);
            acc[i][3] = fmaf(kA.w, xv, acc[i][3]);
            acc[i][4] = fmaf(kB.x, xv, acc[i][4]);
            acc[i][5] = fmaf(kB.y, xv, acc[i][5]);
            acc[i][6] = fmaf(kB.z, xv, acc[i][6]);
            acc[i][7] = fmaf(kB.w, xv, acc[i][7]);
            acc[i][8] = fmaf(kC.x, xv, acc[i][8]);
            acc[i][9] = fmaf(kC.y, xv, acc[i][9]);
        }
        // shift window: position i at d+1 needs value that position i-1 had at d
        const int jn = 64 + ub - 1 - d;
        const float nw = xs[jn + (jn >> 5)];
        wn[3] = wn[2]; wn[2] = wn[1]; wn[1] = wn[0]; wn[0] = nw;
    }

    float buf[4 * OUTD];
    #pragma unroll
    for (int i = 0; i < 4; ++i)
        #pragma unroll
        for (int o = 0; o < OUTD; ++o) buf[i * OUTD + o] = acc[i][o];

    float* yb = y + (size_t)(b * TLEN + t0 + ub) * OUTD;  // 40 consecutive floats, 16B-aligned
    #pragma unroll
    for (int q = 0; q < 10; ++q)
        *(float4*)(yb + q * 4) =
            make_float4(buf[4 * q], buf[4 * q + 1], buf[4 * q + 2], buf[4 * q + 3]);
}

extern "C" void kernel_launch(void* const* d_in, const int* in_sizes, int n_in,
                              void* d_out, int out_size, void* d_ws, size_t ws_size,
                              hipStream_t stream)
{
    const float* x  = (const float*)d_in[0];   // (64, 8192)
    const float* W1 = (const float*)d_in[1];   // (256, 1) -> w1
    const float* W2 = (const float*)d_in[2];   // (256, 256)
    const float* W3 = (const float*)d_in[3];   // (10, 256)
    float* y  = (float*)d_out;
    float* ws = (float*)d_ws;

    float* Pb0 = ws;                    // 65536 floats: power ping
    float* Pb1 = ws + 65536;            // 65536 floats: power pong
    float* Rb  = ws + 131072;           // 640 rows x 256: R[d][o][:]
    float* Kb  = ws + 131072 + 163840;  // 64 x 12

    dim3 blk(256);
    // doubling chain: R_{2^s..2^{s+1}-1} = R_{0..2^s-1} * W2^{2^s};  next power = P*P
    stage_kernel<<<35, blk, 0, stream>>>(W2,  Pb0, W3, Rb +  10 * Hd,  10, 256, W3, Rb, 10);
    stage_kernel<<<35, blk, 0, stream>>>(Pb0, Pb1, Rb, Rb +  20 * Hd,  20, 256, nullptr, nullptr, 0);
    stage_kernel<<<37, blk, 0, stream>>>(Pb1, Pb0, Rb, Rb +  40 * Hd,  40, 256, nullptr, nullptr, 0);
    stage_kernel<<<42, blk, 0, stream>>>(Pb0, Pb1, Rb, Rb +  80 * Hd,  80, 256, nullptr, nullptr, 0);
    stage_kernel<<<52, blk, 0, stream>>>(Pb1, Pb0, Rb, Rb + 160 * Hd, 160, 256, nullptr, nullptr, 0);
    stage_kernel<<<40, blk, 0, stream>>>(Pb0, nullptr, Rb, Rb + 320 * Hd, 320, 0, nullptr, nullptr, 0);
    k_kernel<<<160, blk, 0, stream>>>(Rb, W1, Kb);
    conv_kernel<<<512, blk, 0, stream>>>(x, Kb, y);
}

// Round 2
// 70.893 us; speedup vs baseline: 1.8455x; 1.8455x over previous
//
#include <hip/hip_runtime.h>

#define Hd     256
#define OUTD   10
#define DDEP   64
#define TLEN   8192

static __device__ __forceinline__ int imin(int a, int b) { return a < b ? a : b; }

// Stage kernel: blocks [0, sqBlocks) compute Pout = B*B (4 rows each).
// Blocks [sqBlocks, ...) compute Rdst[j] = Rsrc[j]*B (4 rows each), plus
// K[dstD0 + row/10][row%10] = Rdst_row . w1 (fused). If srcD0>=0 also
// K[srcD0 + row/10][row%10] = Rsrc_row . w1 (used by S0 for K[0..9]).
// If cpDst != null, Rsrc rows are also copied there (S0: W3 -> R0).
__global__ __launch_bounds__(512) void stage2_kernel(
    const float* __restrict__ B, float* __restrict__ Pout, int sqBlocks,
    const float* __restrict__ Rsrc, float* __restrict__ Rdst, int nRrows,
    const float* __restrict__ w1, float* __restrict__ Kb,
    int dstD0, int srcD0, float* __restrict__ cpDst)
{
    __shared__ alignas(16) float Xs[4][Hd];
    __shared__ alignas(16) float red[4][Hd];
    const int tid   = threadIdx.x;
    const int c     = tid & 255;          // output column
    const int half  = tid >> 8;           // j-range half (0/1)
    const bool isSQ = (int)blockIdx.x < sqBlocks;
    const int  j0   = (isSQ ? (int)blockIdx.x : (int)blockIdx.x - sqBlocks) * 4;
    const float* X  = isSQ ? (B + j0 * Hd) : (Rsrc + j0 * Hd);
    const int  rmax = isSQ ? 4 : imin(4, nRrows - j0);

    // stage X rows into LDS (zero-pad beyond rmax)
    for (int i = tid; i < 4 * Hd; i += 512) {
        const int r = i >> 8, cc = i & 255;
        Xs[r][cc] = (r < rmax) ? X[r * Hd + cc] : 0.0f;
    }
    __syncthreads();

    // acc[r] = sum over my j-half of X[r][j]*B[j][c]
    float acc[4] = {0.f, 0.f, 0.f, 0.f};
    const int jbase = half * 128;
    const float* Bc = B + c + jbase * Hd;
    #pragma unroll 2
    for (int j = 0; j < 128; j += 8) {
        float p[8];
        #pragma unroll
        for (int k = 0; k < 8; ++k) p[k] = Bc[(j + k) * Hd];
        #pragma unroll
        for (int r = 0; r < 4; ++r) {
            const float4 xa = *(const float4*)&Xs[r][jbase + j];
            const float4 xb = *(const float4*)&Xs[r][jbase + j + 4];
            acc[r] = fmaf(xa.x, p[0], acc[r]);
            acc[r] = fmaf(xa.y, p[1], acc[r]);
            acc[r] = fmaf(xa.z, p[2], acc[r]);
            acc[r] = fmaf(xa.w, p[3], acc[r]);
            acc[r] = fmaf(xb.x, p[4], acc[r]);
            acc[r] = fmaf(xb.y, p[5], acc[r]);
            acc[r] = fmaf(xb.z, p[6], acc[r]);
            acc[r] = fmaf(xb.w, p[7], acc[r]);
        }
    }

    // combine the two j-halves
    if (half == 1) {
        #pragma unroll
        for (int r = 0; r < 4; ++r) red[r][c] = acc[r];
    }
    __syncthreads();
    const float w1c = w1[c];
    if (half == 0) {
        #pragma unroll
        for (int r = 0; r < 4; ++r) acc[r] += red[r][c];
        float* Out = isSQ ? (Pout + j0 * Hd) : (Rdst + j0 * Hd);
        for (int r = 0; r < rmax; ++r) Out[r * Hd + c] = acc[r];
        if (!isSQ && cpDst != nullptr)
            for (int r = 0; r < rmax; ++r) cpDst[(j0 + r) * Hd + c] = Xs[r][c];
    }
    if (isSQ) return;                      // block-uniform exit

    // K from the freshly computed output rows
    __syncthreads();                       // red reuse barrier
    if (half == 0) {
        #pragma unroll
        for (int r = 0; r < 4; ++r) {
            float v = acc[r] * w1c;
            #pragma unroll
            for (int off = 32; off; off >>= 1) v += __shfl_down(v, off);
            if ((tid & 63) == 0) red[r][tid >> 6] = v;
        }
    }
    __syncthreads();
    if (tid < rmax) {
        const int row = j0 + tid;
        const float kv = red[tid][0] + red[tid][1] + red[tid][2] + red[tid][3];
        const int d = dstD0 + row / 10, o = row % 10;
        Kb[d * 12 + o] = kv;
        if (o == 0) { Kb[d * 12 + 10] = 0.f; Kb[d * 12 + 11] = 0.f; }
    }

    // optional: K from the SOURCE rows (stage 0 only, K[0..9] from W3)
    if (srcD0 >= 0) {
        __syncthreads();
        if (half == 0) {
            #pragma unroll
            for (int r = 0; r < 4; ++r) {
                float v = Xs[r][c] * w1c;
                #pragma unroll
                for (int off = 32; off; off >>= 1) v += __shfl_down(v, off);
                if ((tid & 63) == 0) red[r][tid >> 6] = v;
            }
        }
        __syncthreads();
        if (tid < rmax) {
            const int row = j0 + tid;
            const float kv = red[tid][0] + red[tid][1] + red[tid][2] + red[tid][3];
            const int d = srcD0 + row / 10, o = row % 10;
            Kb[d * 12 + o] = kv;
            if (o == 0) { Kb[d * 12 + 10] = 0.f; Kb[d * 12 + 11] = 0.f; }
        }
    }
}

// Causal FIR: y[b,t,o] = sum_{d<64} K[d][o]*x[b,t-d].
__global__ __launch_bounds__(256) void conv_kernel(
    const float* __restrict__ x, const float* __restrict__ Kb,
    float* __restrict__ y)
{
    __shared__ float xs[1160];          // swizzled: phys(j) = j + (j>>5)
    __shared__ alignas(16) float Ks[DDEP * 12];
    const int tid  = threadIdx.x;
    const int b    = blockIdx.x >> 3;
    const int t0   = (blockIdx.x & 7) * 1024;
    const float* xb = x + b * TLEN;

    for (int j = tid; j < 1088; j += 256) {
        const int g = t0 - 64 + j;
        xs[j + (j >> 5)] = (g >= 0) ? xb[g] : 0.0f;
    }
    for (int j = tid; j < DDEP * 12; j += 256) Ks[j] = Kb[j];
    __syncthreads();

    const int ub = tid * 4;
    float acc[4][OUTD];
    #pragma unroll
    for (int i = 0; i < 4; ++i)
        #pragma unroll
        for (int o = 0; o < OUTD; ++o) acc[i][o] = 0.0f;

    float wn[4];
    #pragma unroll
    for (int i = 0; i < 4; ++i) {
        const int j = 64 + ub + i;
        wn[i] = xs[j + (j >> 5)];
    }

    #pragma unroll 8
    for (int d = 0; d < DDEP; ++d) {
        const float4 kA = *(const float4*)&Ks[d * 12];
        const float4 kB = *(const float4*)&Ks[d * 12 + 4];
        const float2 kC = *(const float2*)&Ks[d * 12 + 8];
        #pragma unroll
        for (int i = 0; i < 4; ++i) {
            const float xv = wn[i];
            acc[i][0] = fmaf(kA.x, xv, acc[i][0]);
            acc[i][1] = fmaf(kA.y, xv, acc[i][1]);
            acc[i][2] = fmaf(kA.z, xv, acc[i][2]);
            acc[i][3] = fmaf(kA.w, xv, acc[i][3]);
            acc[i][4] = fmaf(kB.x, xv, acc[i][4]);
            acc[i][5] = fmaf(kB.y, xv, acc[i][5]);
            acc[i][6] = fmaf(kB.z, xv, acc[i][6]);
            acc[i][7] = fmaf(kB.w, xv, acc[i][7]);
            acc[i][8] = fmaf(kC.x, xv, acc[i][8]);
            acc[i][9] = fmaf(kC.y, xv, acc[i][9]);
        }
        const int jn = 64 + ub - 1 - d;
        const float nw = xs[jn + (jn >> 5)];
        wn[3] = wn[2]; wn[2] = wn[1]; wn[1] = wn[0]; wn[0] = nw;
    }

    float buf[4 * OUTD];
    #pragma unroll
    for (int i = 0; i < 4; ++i)
        #pragma unroll
        for (int o = 0; o < OUTD; ++o) buf[i * OUTD + o] = acc[i][o];

    float* yb = y + (size_t)(b * TLEN + t0 + ub) * OUTD;
    #pragma unroll
    for (int q = 0; q < 10; ++q)
        *(float4*)(yb + q * 4) =
            make_float4(buf[4 * q], buf[4 * q + 1], buf[4 * q + 2], buf[4 * q + 3]);
}

extern "C" void kernel_launch(void* const* d_in, const int* in_sizes, int n_in,
                              void* d_out, int out_size, void* d_ws, size_t ws_size,
                              hipStream_t stream)
{
    const float* x  = (const float*)d_in[0];   // (64, 8192)
    const float* w1 = (const float*)d_in[1];   // (256, 1) contiguous
    const float* W2 = (const float*)d_in[2];   // (256, 256)
    const float* W3 = (const float*)d_in[3];   // (10, 256)
    float* y  = (float*)d_out;
    float* ws = (float*)d_ws;

    float* Pb0 = ws;                    // 65536 floats
    float* Pb1 = ws + 65536;            // 65536 floats
    float* Rb  = ws + 131072;           // 640 rows x 256
    float* Kb  = ws + 131072 + 163840;  // 64 x 12

    dim3 blk(512);
    // S0: P1=W2^2; R1=W3*W2; K[0] (from W3), K[1]; copy W3->R0
    stage2_kernel<<<67, blk, 0, stream>>>(W2,  Pb0, 64, W3, Rb + 10*Hd,  10, w1, Kb,  1,  0, Rb);
    // S1: P2=W2^4; R2..3 = R0..1 * P1; K[2..3]
    stage2_kernel<<<69, blk, 0, stream>>>(Pb0, Pb1, 64, Rb, Rb + 20*Hd,  20, w1, Kb,  2, -1, nullptr);
    // S2: P3=W2^8; R4..7; K[4..7]
    stage2_kernel<<<74, blk, 0, stream>>>(Pb1, Pb0, 64, Rb, Rb + 40*Hd,  40, w1, Kb,  4, -1, nullptr);
    // S3: P4=W2^16; R8..15; K[8..15]
    stage2_kernel<<<84, blk, 0, stream>>>(Pb0, Pb1, 64, Rb, Rb + 80*Hd,  80, w1, Kb,  8, -1, nullptr);
    // S4: P5=W2^32; R16..31; K[16..31]
    stage2_kernel<<<104, blk, 0, stream>>>(Pb1, Pb0, 64, Rb, Rb + 160*Hd, 160, w1, Kb, 16, -1, nullptr);
    // S5: R32..63 = R0..31 * P5; K[32..63] (no squaring)
    stage2_kernel<<<80, blk, 0, stream>>>(Pb0, nullptr, 0, Rb, Rb + 320*Hd, 320, w1, Kb, 32, -1, nullptr);
    // conv: y = K (*) x
    conv_kernel<<<512, dim3(256), 0, stream>>>(x, Kb, y);
}